// Round 7
// baseline (13038.576 us; speedup 1.0000x reference)
//
#include <hip/hip_runtime.h>
#include <hip/hip_fp16.h>

// GInvariantLSTMLayer persistent-RNN, round 13.
// Backbone (validated r3/r6/r10/r11/r12): sc1 cache-bypass loads + sc1
// write-through stores, zero fences, "=&v" early-clobber LOAD4, WAITG vmcnt
// ladder, weights in registers (r7), 256 blocks = 128 feature-groups x 2 batch
// halves (r10), direct packed-dword h stores + s_all in LDS (r11), cohort-split
// (r12).
// r12 POST-MORTEM: -400us from barrier cuts; model confirmed (step = serial
// latency chain, ~80% wait at 7.4us/step).
// r13: SECTOR DATAFLOW SYNC. Wave w consumes only features [512w,512w+512) =
// outputs of producer blocks fblk in [32w,32w+32) of its cohort. So:
//  (1) arrival: per-wave fire-and-forget atomic add to the block's sector
//      counter after its own vmcnt drain (no root, no blocking RT);
//  (2) poll: wave w spins on ONE word (its sector, target 128*round); waves
//      desync -> sector load bursts self-stagger;
//  (3) red parity-double-buffered (LDS 128KB, still 1 blk/CU) -> the 2nd
//      __syncthreads deleted; poll separation (>=2 iters between scatter(t+2)
//      and reduce(t)) protects red;
//  (4) h(0) init goes through the per-step store path -> round-1 sector
//      semantics exact.

typedef _Float16 f16x8 __attribute__((ext_vector_type(8)));
typedef float    f32x4 __attribute__((ext_vector_type(4)));
typedef unsigned long long u64;

static __device__ __forceinline__ float fast_sig(float x) {
  return 1.f / (1.f + __expf(-x));
}
static __device__ __forceinline__ float fast_tanh(float x) {
  x = fminf(15.f, fmaxf(-15.f, x));
  const float e = __expf(2.f * x);
  return (e - 1.f) / (e + 1.f);
}

static __device__ __forceinline__ void st_h32(void* p, unsigned v) {
  __hip_atomic_store((unsigned*)p, v, __ATOMIC_RELAXED, __HIP_MEMORY_SCOPE_AGENT);
}

__global__ void __launch_bounds__(256) seq_sum_kernel(const float* __restrict__ X,
                                                      float* s_all) {
  const int gw   = (int)((blockIdx.x * blockDim.x + threadIdx.x) >> 6);
  const int lane = threadIdx.x & 63;
  const int n = gw >> 9, t = gw & 511;
  const float4* p = (const float4*)(X + ((size_t)gw << 10));
  float s = 0.f;
#pragma unroll
  for (int i = 0; i < 4; ++i) {
    const float4 v = p[lane + (i << 6)];
    s += (v.x + v.y) + (v.z + v.w);
  }
#pragma unroll
  for (int off = 32; off; off >>= 1) s += __shfl_xor(s, off);
  if (lane == 0) s_all[(t << 6) + n] = s;
}

__global__ void bar_init_kernel(unsigned* bar) {
  bar[threadIdx.x]       = 0u;
  bar[threadIdx.x + 256] = 0u;
  bar[threadIdx.x + 512] = 0u;
  bar[threadIdx.x + 768] = 0u;
}

// Issue 4 sc1 dwordx4 loads from one 4-KB window (one address pair, imm offsets).
// "=&v" early-clobber: outputs must NOT alias the address pair (r9 crash fix).
#define LOAD4(d0, d1, d2, d3, addr)                                         \
  asm volatile("global_load_dwordx4 %0, %4, off sc1\n\t"                    \
               "global_load_dwordx4 %1, %4, off offset:1024 sc1\n\t"        \
               "global_load_dwordx4 %2, %4, off offset:2048 sc1\n\t"        \
               "global_load_dwordx4 %3, %4, off offset:3072 sc1"            \
               : "=&v"(d0), "=&v"(d1), "=&v"(d2), "=&v"(d3)                 \
               : "v"(addr)                                                  \
               : "memory")

// Wait until <= n vmem ops outstanding; ties the 4 fragments of one chunk so
// their MFMAs cannot hoist above; memory clobber pins all other mem ops.
#define WAITG4(n, A, b)                                                     \
  asm volatile("s_waitcnt vmcnt(" #n ")"                                    \
               : "+v"(A[(b)]), "+v"(A[(b) + 1]), "+v"(A[(b) + 2]),          \
                 "+v"(A[(b) + 3])                                           \
               :                                                            \
               : "memory")

// 4 K-chunks of 32 feed 4 column tiles; weights from registers only.
#define KMATH4(A, b)                                                        \
  _Pragma("unroll")                                                         \
  for (int i_ = (b); i_ < (b) + 4; ++i_) {                                  \
    acc[0] = __builtin_amdgcn_mfma_f32_16x16x32_f16(A[i_], Wr[i_][0],       \
                                                    acc[0], 0, 0, 0);       \
    acc[1] = __builtin_amdgcn_mfma_f32_16x16x32_f16(A[i_], Wr[i_][1],       \
                                                    acc[1], 0, 0, 0);       \
    acc[2] = __builtin_amdgcn_mfma_f32_16x16x32_f16(A[i_], Wr[i_][2],       \
                                                    acc[2], 0, 0, 0);       \
    acc[3] = __builtin_amdgcn_mfma_f32_16x16x32_f16(A[i_], Wr[i_][3],       \
                                                    acc[3], 0, 0, 0);       \
  }

// Scatter one batch-group's partials into rr (parity buffer), bank-swizzled
// with key=(n&15)^(n>>4): write side 2-way max, read side balanced (conflicts
// measured 0 in r11/r12).
#define SCATTER(bt)                                                         \
  _Pragma("unroll")                                                         \
  for (int ct_ = 0; ct_ < 4; ++ct_) {                                       \
    const int kf_ = ct_ * 4 + (cc >> 2);                                    \
    _Pragma("unroll")                                                       \
    for (int v_ = 0; v_ < 4; ++v_) {                                        \
      const int n_  = (bt) * 16 + (q << 2) + v_;                            \
      const int key = (n_ & 15) ^ (n_ >> 4);                                \
      rr[wave][n_][((kf_ ^ key) << 2) + (cc & 3)] = acc[ct_][v_];           \
    }                                                                       \
  }

__global__ void __launch_bounds__(256, 1) ginv_lstm_persist(
    const float* __restrict__ lin_W, const float* __restrict__ inv_w,
    const float* __restrict__ inv_b, const float* __restrict__ lin_b,
    const float* s_all, const float* __restrict__ H0,
    _Float16* hb0, _Float16* hb1, unsigned* bar, float* out) {
  // 128 KB LDS -> 1 block/CU. red is parity-double-buffered (sync cut 3).
  __shared__ __align__(16) float s_lds[512][32];      // 64 KB: s_all slice
  __shared__ __align__(16) float red[2][4][32][64];   // 64 KB: partials x2
  const int blk = blockIdx.x;
  const int tid = threadIdx.x;
  _Float16* hbuf[2] = {hb0, hb1};

  const int fblk = blk & 127;  // feature group: features fblk*16 .. fblk*16+15
  const int nh   = blk >> 7;   // batch half:   batches  nh*32 .. nh*32+31

  const int wave = tid >> 6;   // K-quarter owner = consumed sector id
  const int lane = tid & 63;
  const int q    = lane >> 4;
  const int cc   = lane & 15;

  // Sector counters: cohort nh, sector s at bar + (nh<<8) + (s<<4) (64 B apart).
  unsigned* my_sector  = bar + (nh << 8) + ((fblk >> 5) << 4);  // arrival target
  unsigned* rd_sector  = bar + (nh << 8) + (wave << 4);         // poll target

  // ---- stage this wave's weight slice fp32 -> fp16 REGISTERS (once) ----
  // Column c = ct*16+cc maps to (kf = c>>2, gate = c&3); element e of fragment
  // (kc, ct) = lin_W[g][fblk*16+kf][wave*512 + kc*32 + q*8 + e].
  f16x8 Wr[16][4];
#pragma unroll
  for (int ct = 0; ct < 4; ++ct) {
    const int kf = ct * 4 + (cc >> 2), g = cc & 3;
    const float* wrow =
        lin_W + (((size_t)(g * 2048 + fblk * 16 + kf)) << 11) + wave * 512 + q * 8;
#pragma unroll
    for (int kc = 0; kc < 16; ++kc) {
      const float4 va = *(const float4*)(wrow + kc * 32);
      const float4 vb = *(const float4*)(wrow + kc * 32 + 4);
      f16x8 f;
      f[0] = (_Float16)va.x; f[1] = (_Float16)va.y;
      f[2] = (_Float16)va.z; f[3] = (_Float16)va.w;
      f[4] = (_Float16)vb.x; f[5] = (_Float16)vb.y;
      f[6] = (_Float16)vb.z; f[7] = (_Float16)vb.w;
      Wr[kc][ct] = f;
    }
  }

  // ---- preload s_all slice for this batch half into LDS (once, float4) ----
  // Visible to all threads after the first in-loop __syncthreads (scatter sync).
  for (int i = tid; i < 512 * 8; i += 256) {
    const int t4 = i >> 3, nl4 = (i & 7) << 2;
    *(float4*)&s_lds[t4][nl4] =
        *(const float4*)&s_all[(t4 << 6) + (nh << 5) + nl4];
  }

  // ---- gate ownership: thread (wave,lane) finalizes n = wave*8 + (lane>>3),
  //      features c = 2*(lane&7) + kk, kk = 0,1 (ADJACENT -> one packed dword) ----
  const int nloc = (wave << 3) + (lane >> 3);  // 0..31
  const int c0   = (lane & 7) << 1;            // 0,2,..,14
  float iw[2][4], ibb[2][4];
#pragma unroll
  for (int kk = 0; kk < 2; ++kk) {
    const int Kg = fblk * 16 + c0 + kk;
#pragma unroll
    for (int g = 0; g < 4; ++g) {
      iw[kk][g]  = inv_w[(g << 11) + Kg];
      ibb[kk][g] = inv_b[(g << 11) + Kg] + lin_b[(g << 11) + Kg];
    }
  }

  // Fragment (bt, kc): h[n = nh*32 + bt*16 + cc][j = wave*512 + kc*32 + q*8 + e]
  // -> packed byte ((nh*2+bt)<<16) + ((wave*16+kc)<<10) + (cc<<6) + (q<<4).
  const int ld_base = ((nh * 2) << 16) + (wave << 14) + (cc << 6) + (q << 4);
  // Direct h store: n = nh*32+nloc, j = fblk*16+c0 (+1) -> dword-aligned pair
  // (verified identical to packed h_off in r11/r12).
  const int hst_off = ((nh * 2 + (nloc >> 4)) << 16) + ((fblk >> 1) << 10) +
                      ((nloc & 15) << 6) + ((fblk & 1) << 5) + (c0 << 1);
  const int key = (nloc & 15) ^ (nloc >> 4);

  // ---- init h(0) THROUGH THE STORE PATH (exact sector semantics, round 1) ----
  {
    const float* h0p = H0 + ((nh << 5) + nloc) * 2048 + (fblk << 4) + c0;
    const unsigned lo = __builtin_bit_cast(unsigned short, (_Float16)h0p[0]);
    const unsigned hi = __builtin_bit_cast(unsigned short, (_Float16)h0p[1]);
    st_h32((char*)hb0 + hst_off, lo | (hi << 16));
  }
  asm volatile("s_waitcnt vmcnt(0)" ::: "memory");  // h(0) stores drained
  if ((tid & 63) == 0)
    __hip_atomic_fetch_add(my_sector, 1u, __ATOMIC_RELAXED,
                           __HIP_MEMORY_SCOPE_AGENT);  // fire-and-forget

  float cst[2] = {0.f, 0.f};
  float hnew[2] = {0.f, 0.f};

  for (int t = 0; t < 512; ++t) {
    // ---- per-wave sector poll: ONE word; wave w waits for its 32 producers
    // (x4 waves each). Target = 128*(t+1). All lanes load the same address
    // (single broadcast transaction); uniform branch.
    {
      const unsigned target = (unsigned)(t + 1) << 7;
      unsigned guard = 0;
      while (__hip_atomic_load(rd_sector, __ATOMIC_RELAXED,
                               __HIP_MEMORY_SCOPE_AGENT) < target) {
        __builtin_amdgcn_s_sleep(1);
        if (++guard > (1u << 23)) break;  // anti-hang; never fires when resident
      }
    }

    const char* hpb = (const char*)hbuf[t & 1] + ld_base;
    float (*rr)[32][64] = red[t & 1];

    f16x8 pa[16], pb[16];  // 2 groups x 16 fragments = 128 VGPRs
    f32x4 acc[4];          // 4 column tiles (16 features x 4 gates)

    // issue G0 (bt=0) -> pa, G1 (bt=1) -> pb   (16 loads each; 4 addr pairs/group)
#pragma unroll
    for (int w = 0; w < 4; ++w)
      LOAD4(pa[w * 4], pa[w * 4 + 1], pa[w * 4 + 2], pa[w * 4 + 3],
            hpb + (w << 12));
#pragma unroll
    for (int w = 0; w < 4; ++w)
      LOAD4(pb[w * 4], pb[w * 4 + 1], pb[w * 4 + 2], pb[w * 4 + 3],
            hpb + 65536 + (w << 12));

    // ---- G0: 4-fragment wait ladder interleaved with MFMA chunks ----
#pragma unroll
    for (int ct = 0; ct < 4; ++ct) acc[ct] = (f32x4){0.f, 0.f, 0.f, 0.f};
    WAITG4(28, pa, 0);  KMATH4(pa, 0);
    WAITG4(24, pa, 4);  KMATH4(pa, 4);
    WAITG4(20, pa, 8);  KMATH4(pa, 8);
    WAITG4(16, pa, 12); KMATH4(pa, 12);
    SCATTER(0);

    // ---- G1 ----
#pragma unroll
    for (int ct = 0; ct < 4; ++ct) acc[ct] = (f32x4){0.f, 0.f, 0.f, 0.f};
    WAITG4(12, pb, 0);  KMATH4(pb, 0);
    WAITG4(8,  pb, 4);  KMATH4(pb, 4);
    WAITG4(4,  pb, 8);  KMATH4(pb, 8);
    WAITG4(0,  pb, 12); KMATH4(pb, 12);
    SCATTER(1);

    __syncthreads();  // scatter(t) -> reduce(t); the ONLY block barrier per step

    // ---- reduce 4 K-quarters + gates; sv from LDS (no global load) ----
    const float sv = s_lds[t][nloc];
#pragma unroll
    for (int kk = 0; kk < 2; ++kk) {
      const int off = ((c0 + kk) ^ key) << 2;
      f32x4 zz = *(const f32x4*)&rr[0][nloc][off];
#pragma unroll
      for (int w = 1; w < 4; ++w) zz += *(const f32x4*)&rr[w][nloc][off];
      const float zi = zz[0] + sv * iw[kk][0] + ibb[kk][0];
      const float zf = zz[1] + sv * iw[kk][1] + ibb[kk][1];
      const float zg = zz[2] + sv * iw[kk][2] + ibb[kk][2];
      const float zo = zz[3] + sv * iw[kk][3] + ibb[kk][3];
      const float ig = fast_sig(zi);
      const float fg = fast_sig(zf);
      const float gg = fast_tanh(zg);
      const float og = fast_sig(zo);
      const float cn = fg * cst[kk] + ig * gg;
      cst[kk] = cn;
      hnew[kk] = og * fast_tanh(cn);
    }

    // Direct packed-dword h store, per-wave drain, fire-and-forget arrival.
    {
      const unsigned lo = __builtin_bit_cast(unsigned short, (_Float16)hnew[0]);
      const unsigned hi = __builtin_bit_cast(unsigned short, (_Float16)hnew[1]);
      st_h32((char*)hbuf[(t + 1) & 1] + hst_off, lo | (hi << 16));
    }
    asm volatile("s_waitcnt vmcnt(0)" ::: "memory");  // own wave's store drained
    if ((tid & 63) == 0)
      __hip_atomic_fetch_add(my_sector, 1u, __ATOMIC_RELAXED,
                             __HIP_MEMORY_SCOPE_AGENT);
  }

  // Epilogue: hnew holds h(512) for (n = nh*32+nloc, f = fblk*16+c0+kk).
#pragma unroll
  for (int kk = 0; kk < 2; ++kk)
    out[((fblk * 16 + c0 + kk) << 6) + (nh << 5) + nloc] = hnew[kk];
}

extern "C" void kernel_launch(void* const* d_in, const int* in_sizes, int n_in,
                              void* d_out, int out_size, void* d_ws, size_t ws_size,
                              hipStream_t stream) {
  const float* X     = (const float*)d_in[0];
  const float* H0    = (const float*)d_in[1];
  const float* inv_w = (const float*)d_in[2];
  const float* inv_b = (const float*)d_in[3];
  const float* lin_W = (const float*)d_in[4];
  const float* lin_b = (const float*)d_in[5];
  float* out = (float*)d_out;

  const size_t S_BYTES = 512 * 64 * 4;
  const size_t BAR_PAD = 4096;
  const size_t H_BYTES = 64 * 2048 * 2;
  const size_t NEED = S_BYTES + BAR_PAD + 2 * H_BYTES;

  float*    s_all;
  unsigned* bar;
  _Float16* hb[2];
  if (ws_size >= NEED) {
    char* ws = (char*)d_ws;
    s_all = (float*)ws;
    bar   = (unsigned*)(ws + S_BYTES);
    for (int i = 0; i < 2; ++i)
      hb[i] = (_Float16*)(ws + S_BYTES + BAR_PAD + (size_t)i * H_BYTES);
  } else {
    // Fallback: s_all in d_out (read only during init preload; every block's
    // epilogue out-write happens after its round-512 poll, which transitively
    // requires all blocks past init), bar + h buffers in X's tail (X fully
    // consumed by seq_sum_kernel first on-stream; harness restores X per launch).
    s_all = (float*)d_out;
    char* xt = (char*)d_in[0] + (size_t)64 * 512 * 1024 * 4 -
               (BAR_PAD + 2 * H_BYTES);
    bar = (unsigned*)xt;
    for (int i = 0; i < 2; ++i)
      hb[i] = (_Float16*)(xt + BAR_PAD + (size_t)i * H_BYTES);
  }

  seq_sum_kernel<<<8192, 256, 0, stream>>>(X, s_all);
  bar_init_kernel<<<1, 256, 0, stream>>>(bar);
  ginv_lstm_persist<<<256, 256, 0, stream>>>(lin_W, inv_w, inv_b, lin_b, s_all, H0,
                                             hb[0], hb[1], bar, out);
}